// Round 13
// baseline (177.557 us; speedup 1.0000x reference)
//
#include <hip/hip_runtime.h>
#include <stdint.h>

// Soft Decision Tree forward, MI355X (gfx950)
//   xsplit: X -> Xs = bf16(X) [32768][800]                  (r7/r11-validated)
//   wsplit: W_inner -> Ws = bf16 [1024][800], bias[1024]    (r7/r11-validated)
//   gemm8 : P = sigmoid(bias + Xs @ Ws^T), K=800 bf16 MFMA  (r11-validated, BYTE-IDENTICAL)
//   tree  : heap p-row (r11-validated) + wl-hoisted GEMV    (SINGLE change this round)
//   penalty: tree reduction of leaf sums                    (validated)

#define BROWS 32768
#define KDIM  784
#define NNODE 1023
#define NP    1024
#define NLEAF 1024
#define OUTD  10
#define NDEPTH 10
#define LAMDA 1e-3f

#define GKS   800           // Xs row stride
#define GKW   800           // Ws row stride
#define NT    25            // K tiles of 32

typedef __attribute__((ext_vector_type(8))) short short8;
typedef __attribute__((ext_vector_type(4))) float f32x4;

__device__ __forceinline__ unsigned short f2bf(float f) {
    unsigned int u = __float_as_uint(f);
    u = u + 0x7FFFu + ((u >> 16) & 1u);   // RNE
    return (unsigned short)(u >> 16);
}
__device__ __forceinline__ float bf2f(unsigned short h) {
    return __uint_as_float(((unsigned int)h) << 16);
}

// ============================ Pass X: cast X -> bf16 =============================
__global__ __launch_bounds__(256)
void sdt_xsplit(const float* __restrict__ X, unsigned short* __restrict__ Xs)
{
    const int g   = blockIdx.x * 256 + threadIdx.x;   // [0, 32768*100)
    const int row = g / 100, grp = g % 100;
    unsigned int hi[4];
    if (grp < 98) {
        const float4* src = reinterpret_cast<const float4*>(&X[(size_t)row * KDIM + grp * 8]);
        const float4 v0 = src[0], v1 = src[1];
        const float v[8] = {v0.x, v0.y, v0.z, v0.w, v1.x, v1.y, v1.z, v1.w};
#pragma unroll
        for (int i = 0; i < 4; ++i)
            hi[i] = (unsigned int)f2bf(v[2*i]) | ((unsigned int)f2bf(v[2*i+1]) << 16);
    } else {
#pragma unroll
        for (int i = 0; i < 4; ++i) hi[i] = 0u;
    }
    *reinterpret_cast<uint4*>(&Xs[(size_t)row * GKS + grp * 8]) = make_uint4(hi[0], hi[1], hi[2], hi[3]);
}

// ============================ Pass W: cast W -> bf16 =============================
__global__ __launch_bounds__(256)
void sdt_wsplit(const float* __restrict__ Wi, unsigned short* __restrict__ Ws,
                float* __restrict__ bias)
{
    const int row = blockIdx.x;          // 0..1023
    const int tid = threadIdx.x;
    for (int c = tid; c < GKW; c += 256) {
        unsigned short v = 0;
        if (row < NNODE && c < KDIM) v = f2bf(Wi[(size_t)row * (KDIM + 1) + 1 + c]);
        Ws[(size_t)row * GKW + c] = v;
    }
    if (tid == 0) bias[row] = (row < NNODE) ? Wi[(size_t)row * (KDIM + 1)] : 0.f;
}

// ===================== Pass A: 256x256, BK=32, 4-buffer counted-vmcnt MFMA =====================
#define BAR() { __builtin_amdgcn_sched_barrier(0); __builtin_amdgcn_s_barrier(); __builtin_amdgcn_sched_barrier(0); }

// stage tile kt into buffer (kt&3): 2 A-loads + 2 B-loads per thread (16B each)
#define STAGE(ktn)                                                                    \
    {                                                                                 \
        const int kt_ = (ktn);                                                        \
        const int kk_ = kt_ * 32;                                                     \
        unsigned short* ab_ = lds + (kt_ & 3) * 16384;                                \
        unsigned short* bb_ = ab_ + 8192;                                             \
        _Pragma("unroll")                                                             \
        for (int j = 0; j < 2; ++j)                                                   \
            __builtin_amdgcn_global_load_lds(                                         \
                (const __attribute__((address_space(1))) void*)(pA[j] + kk_),         \
                (__attribute__((address_space(3))) void*)(ab_ + (j * 512 + wave * 64) * 8), \
                16, 0, 0);                                                            \
        _Pragma("unroll")                                                             \
        for (int j = 0; j < 2; ++j)                                                   \
            __builtin_amdgcn_global_load_lds(                                         \
                (const __attribute__((address_space(1))) void*)(pB[j] + kk_),         \
                (__attribute__((address_space(3))) void*)(bb_ + (j * 512 + wave * 64) * 8), \
                16, 0, 0);                                                            \
    }

// fragment reads: row stride 32 shorts (64B); slot swizzle q4 ^ ((row>>1)&3)
#define LDA4(dst, mb, ab_)                                                            \
    _Pragma("unroll")                                                                 \
    for (int mi = 0; mi < 4; ++mi) {                                                  \
        const int row_ = wr * 128 + ((mb) + mi) * 16 + fr;                            \
        dst[mi] = *reinterpret_cast<const short8*>(                                   \
            (ab_) + row_ * 32 + ((q4 ^ ((row_ >> 1) & 3)) * 8));                      \
    }

#define LDB4(dst, bb_)                                                                \
    _Pragma("unroll")                                                                 \
    for (int n = 0; n < 4; ++n) {                                                     \
        const int row_ = wc * 64 + n * 16 + fr;                                       \
        dst[n] = *reinterpret_cast<const short8*>(                                    \
            (bb_) + row_ * 32 + ((q4 ^ ((row_ >> 1) & 3)) * 8));                      \
    }

#define MFMA16(mb, av, bv)                                                            \
    _Pragma("unroll")                                                                 \
    for (int mi = 0; mi < 4; ++mi)                                                    \
        _Pragma("unroll")                                                             \
        for (int n = 0; n < 4; ++n)                                                   \
            acc[(mb) + mi][n] = __builtin_amdgcn_mfma_f32_16x16x32_bf16(              \
                av[mi], bv[n], acc[(mb) + mi][n], 0, 0, 0);

__global__ __launch_bounds__(512, 2)
void sdt_gemm8(const unsigned short* __restrict__ Xs, const unsigned short* __restrict__ Ws,
               const float* __restrict__ bias, unsigned short* __restrict__ P)
{
    __shared__ __align__(16) unsigned short lds[65536];   // 128 KB = 4 buf x (A 16KB + B 16KB)

    const int tid  = threadIdx.x;
    const int wave = tid >> 6, lane = tid & 63;
    const int wr = wave >> 2, wc = wave & 3;              // 2x4 wave grid -> 128x64 per wave
    // XCD-aware swizzle: 512 blocks, 64 contiguous per XCD
    const int b  = blockIdx.x;
    const int wg = (b & 7) * 64 + (b >> 3);
    const int col0 = (wg & 3) * 256;
    const int row0 = (wg >> 2) * 256;

    const int fr = lane & 15;
    const int q4 = lane >> 4;

    f32x4 acc[8][4];
#pragma unroll
    for (int i = 0; i < 8; ++i)
#pragma unroll
        for (int j = 0; j < 4; ++j) acc[i][j] = (f32x4)0.f;

    // staging sources: chunk c = j*512 + tid -> (r = c>>2, slot = c&3,
    // logical kc = slot ^ ((r>>1)&3)); global addr pre-inverse-swizzled.
    const unsigned short* pA[2];
    const unsigned short* pB[2];
#pragma unroll
    for (int j = 0; j < 2; ++j) {
        const int c = j * 512 + tid;
        const int r = c >> 2;
        const int kc = (c & 3) ^ ((r >> 1) & 3);
        pA[j] = Xs + (size_t)(row0 + r) * GKS + kc * 8;
        pB[j] = Ws + (size_t)(col0 + r) * GKW + kc * 8;
    }

    STAGE(0);
    STAGE(1);
    asm volatile("s_waitcnt vmcnt(4)" ::: "memory");   // tile 0 staged; tile 1 in flight
    BAR();

#pragma unroll 1
    for (int kt = 0; kt < NT; ++kt) {
        const unsigned short* ab = lds + (kt & 3) * 16384;
        const unsigned short* bb = ab + 8192;
        short8 a[4], bfr[4];

        // ---- phase 0: m0-3 ----
        LDA4(a, 0, ab);
        LDB4(bfr, bb);
        if (kt + 2 < NT) STAGE(kt + 2);
        BAR();
        __builtin_amdgcn_s_setprio(1);
        MFMA16(0, a, bfr);
        __builtin_amdgcn_s_setprio(0);
        BAR();
        // ---- phase 1: m4-7 ----
        LDA4(a, 4, ab);
        // steady state: vmcnt(4) drains S(kt+1); tail: full drain (race-free)
        if (kt < NT - 2) { asm volatile("s_waitcnt vmcnt(4)" ::: "memory"); }
        else             { asm volatile("s_waitcnt vmcnt(0)" ::: "memory"); }
        BAR();
        __builtin_amdgcn_s_setprio(1);
        MFMA16(4, a, bfr);
        __builtin_amdgcn_s_setprio(0);
        BAR();
    }

    // ---- epilogue: bias + sigmoid, per-wave LDS transpose, coalesced stores ----
    __syncthreads();
    unsigned short* tr = lds + wave * 8192;   // 16 KB per wave (128 rows x 64 cols bf16)
    float bv[4];
#pragma unroll
    for (int n = 0; n < 4; ++n) bv[n] = bias[col0 + wc * 64 + n * 16 + fr];

#pragma unroll
    for (int m = 0; m < 8; ++m)
#pragma unroll
        for (int reg = 0; reg < 4; ++reg) {
            const int rl = m * 16 + q4 * 4 + reg;
#pragma unroll
            for (int n = 0; n < 4; ++n) {
                const float z = acc[m][n][reg] + bv[n];
                const float p = 1.f / (1.f + __expf(-z));
                tr[rl * 64 + n * 16 + fr] = f2bf(p);
            }
        }
    // wave-private readback (no barrier needed)
#pragma unroll
    for (int it = 0; it < 16; ++it) {
        const int r  = it * 8 + (lane >> 3);
        const int c8 = (lane & 7) * 8;
        const uint4 v = *reinterpret_cast<const uint4*>(tr + r * 64 + c8);
        *reinterpret_cast<uint4*>(
            &P[(size_t)(row0 + wr * 128 + r) * NP + col0 + wc * 64 + c8]) = v;
    }
}

// ===================== Pass B: tree sweep + leaf GEMV + leaf sums =====================
// Heap p-row (r11-validated). SINGLE CHANGE: wl-hoisted GEMV — all 8 rows' m4 in
// registers (static indexing), wl read ONCE per output, stride-9 transpose reduce.
__global__ __launch_bounds__(256)
void sdt_tree(const unsigned short* __restrict__ P, const float* __restrict__ Wl,
              float* __restrict__ Y, float* __restrict__ leafsum)
{
    __shared__ float wl[OUTD * NLEAF];   // 40960 B
    __shared__ float buf[4][1032];       // 16512 B (heap p row / leaf-sum scratch)
    __shared__ float rd2[4][584];        // 9344 B  (y transpose, stride 9)
    const int tid = threadIdx.x;
    const int wave = tid >> 6, lane = tid & 63;

    for (int idx = tid; idx < (OUTD * NLEAF) / 4; idx += 256)
        reinterpret_cast<float4*>(wl)[idx] = reinterpret_cast<const float4*>(Wl)[idx];
    __syncthreads();

    float lsum[16];
#pragma unroll
    for (int i = 0; i < 16; ++i) lsum[i] = 0.f;

    float m4a[8][16];                    // all static indexing (fully unrolled)
    float* pl = buf[wave];
    float* rw = rd2[wave];
    const int rowbase = blockIdx.x * 32 + wave * 8;

    // ---- phase 1: per row, stage p -> heap LDS, walk + expand into m4a[r] ----
#pragma unroll
    for (int r = 0; r < 8; ++r) {
        const int row = rowbase + r;
        const uint4* prow = reinterpret_cast<const uint4*>(P + (size_t)row * NP);
        const uint4 v0 = prow[lane];
        const uint4 v1 = prow[lane + 64];
        {
            const int b0 = 1 + lane * 8;          // heap shift +1
            pl[b0 + 0] = bf2f((unsigned short)(v0.x & 0xffffu));
            pl[b0 + 1] = bf2f((unsigned short)(v0.x >> 16));
            pl[b0 + 2] = bf2f((unsigned short)(v0.y & 0xffffu));
            pl[b0 + 3] = bf2f((unsigned short)(v0.y >> 16));
            pl[b0 + 4] = bf2f((unsigned short)(v0.z & 0xffffu));
            pl[b0 + 5] = bf2f((unsigned short)(v0.z >> 16));
            pl[b0 + 6] = bf2f((unsigned short)(v0.w & 0xffffu));
            pl[b0 + 7] = bf2f((unsigned short)(v0.w >> 16));
            const int b1 = 1 + (lane + 64) * 8;
            pl[b1 + 0] = bf2f((unsigned short)(v1.x & 0xffffu));
            pl[b1 + 1] = bf2f((unsigned short)(v1.x >> 16));
            pl[b1 + 2] = bf2f((unsigned short)(v1.y & 0xffffu));
            pl[b1 + 3] = bf2f((unsigned short)(v1.y >> 16));
            pl[b1 + 4] = bf2f((unsigned short)(v1.z & 0xffffu));
            pl[b1 + 5] = bf2f((unsigned short)(v1.z >> 16));
            pl[b1 + 6] = bf2f((unsigned short)(v1.w & 0xffffu));
            pl[b1 + 7] = bf2f((unsigned short)(v1.w >> 16));
        }

        // tree walk levels 0-5 (heap: node 1 root, children 2n, 2n+1)
        float mu = 1.f; int node = 1;
#pragma unroll
        for (int d = 0; d < 6; ++d) {
            const int bit = (lane >> (5 - d)) & 1;
            const float pv = pl[node];
            mu *= bit ? (1.f - pv) : pv;
            node = 2 * node + bit;
        }
        // expansion levels 6-9 (aligned vector reads)
        float m1[2], m2[4], m3[8];
        {
            const float pv = pl[64 + lane];
            m1[0] = mu * pv; m1[1] = mu * (1.f - pv);
        }
        {
            const float2 p7 = *reinterpret_cast<const float2*>(&pl[128 + 2 * lane]);
            m2[0] = m1[0] * p7.x; m2[1] = m1[0] * (1.f - p7.x);
            m2[2] = m1[1] * p7.y; m2[3] = m1[1] * (1.f - p7.y);
        }
        {
            const float4 p8 = *reinterpret_cast<const float4*>(&pl[256 + 4 * lane]);
            const float p8v[4] = {p8.x, p8.y, p8.z, p8.w};
#pragma unroll
            for (int i = 0; i < 4; ++i) {
                m3[2 * i] = m2[i] * p8v[i]; m3[2 * i + 1] = m2[i] * (1.f - p8v[i]);
            }
        }
        {
            const float4 pa = *reinterpret_cast<const float4*>(&pl[512 + 8 * lane]);
            const float4 pb = *reinterpret_cast<const float4*>(&pl[512 + 8 * lane + 4]);
            const float p9v[8] = {pa.x, pa.y, pa.z, pa.w, pb.x, pb.y, pb.z, pb.w};
#pragma unroll
            for (int i = 0; i < 8; ++i) {
                m4a[r][2 * i]     = m3[i] * p9v[i];
                m4a[r][2 * i + 1] = m3[i] * (1.f - p9v[i]);
            }
        }
#pragma unroll
        for (int i = 0; i < 16; ++i) lsum[i] += m4a[r][i];
    }

    // ---- phase 2: GEMV, wl read once per output; stride-9 transpose reduce ----
    const int row8 = lane >> 3, oct = lane & 7;
#pragma unroll
    for (int o = 0; o < OUTD; ++o) {
        const float4 w40 = *reinterpret_cast<const float4*>(&wl[o * NLEAF + lane * 16 + 0]);
        const float4 w41 = *reinterpret_cast<const float4*>(&wl[o * NLEAF + lane * 16 + 4]);
        const float4 w42 = *reinterpret_cast<const float4*>(&wl[o * NLEAF + lane * 16 + 8]);
        const float4 w43 = *reinterpret_cast<const float4*>(&wl[o * NLEAF + lane * 16 + 12]);
#pragma unroll
        for (int r = 0; r < 8; ++r) {
            float s = 0.f;
            s = fmaf(m4a[r][0],  w40.x, s); s = fmaf(m4a[r][1],  w40.y, s);
            s = fmaf(m4a[r][2],  w40.z, s); s = fmaf(m4a[r][3],  w40.w, s);
            s = fmaf(m4a[r][4],  w41.x, s); s = fmaf(m4a[r][5],  w41.y, s);
            s = fmaf(m4a[r][6],  w41.z, s); s = fmaf(m4a[r][7],  w41.w, s);
            s = fmaf(m4a[r][8],  w42.x, s); s = fmaf(m4a[r][9],  w42.y, s);
            s = fmaf(m4a[r][10], w42.z, s); s = fmaf(m4a[r][11], w42.w, s);
            s = fmaf(m4a[r][12], w43.x, s); s = fmaf(m4a[r][13], w43.y, s);
            s = fmaf(m4a[r][14], w43.z, s); s = fmaf(m4a[r][15], w43.w, s);
            rw[lane * 9 + r] = s;          // stride-9: <=2-way banks
        }
        // wave-private transpose reduce: lane(row8,oct) sums source-lanes oct*8..+7
        float t = 0.f;
#pragma unroll
        for (int j = 0; j < 8; ++j) t += rw[(oct * 8 + j) * 9 + row8];
        t += __shfl_xor(t, 1, 64);
        t += __shfl_xor(t, 2, 64);
        t += __shfl_xor(t, 4, 64);
        if (oct == 0) Y[(size_t)(rowbase + row8) * OUTD + o] = t;
    }

    // ---- leaf sums ----
    __syncthreads();
#pragma unroll
    for (int i = 0; i < 16; ++i) {
        const int ii = (i + lane) & 15;
        buf[wave][lane * 16 + ii] = lsum[ii];
    }
    __syncthreads();
    for (int idx = tid; idx < NLEAF; idx += 256) {
        const float s = buf[0][idx] + buf[1][idx] + buf[2][idx] + buf[3][idx];
        atomicAdd(&leafsum[idx], s);
    }
}

// ============================ Pass C: penalty ============================
__global__ __launch_bounds__(1024)
void sdt_penalty(const float* __restrict__ leafsum, float* __restrict__ pen_out)
{
    __shared__ float t[NLEAF];
    __shared__ float red1[1024];
    const int tid = threadIdx.x;
    t[tid] = leafsum[tid];
    __syncthreads();
    float pen = 0.f;
    for (int d = NDEPTH; d >= 1; --d) {
        const int n = 1 << d;
        if (tid < n) {
            const float num = t[tid];
            const float par = t[tid & ~1] + t[tid | 1];
            const float a = num / par;
            const float coeff = LAMDA * exp2f((float)(1 - d));
            pen -= 0.5f * coeff * (logf(a) + logf(1.f - a));
        }
        float s = 0.f;
        if (tid < (n >> 1)) s = t[2 * tid] + t[2 * tid + 1];
        __syncthreads();
        if (tid < (n >> 1)) t[tid] = s;
        __syncthreads();
    }
    red1[tid] = pen;
    __syncthreads();
    for (int off = 512; off >= 1; off >>= 1) {
        if (tid < off) red1[tid] += red1[tid + off];
        __syncthreads();
    }
    if (tid == 0) pen_out[0] = red1[0];
}

// ================================ launch ================================
extern "C" void kernel_launch(void* const* d_in, const int* in_sizes, int n_in,
                              void* d_out, int out_size, void* d_ws, size_t ws_size,
                              hipStream_t stream)
{
    const float* X  = (const float*)d_in[0];
    const float* Wi = (const float*)d_in[1];
    const float* Wl = (const float*)d_in[2];
    float* Y   = (float*)d_out;
    float* pen = Y + (size_t)BROWS * OUTD;

    char* ws = (char*)d_ws;
    const size_t P_BYTES  = (size_t)BROWS * NP * 2;            // 67,108,864
    const size_t XS_BYTES = (size_t)BROWS * GKS * 2;           // 52,428,800
    const size_t WS_BYTES = (size_t)NP * GKW * 2;              // 1,638,400

    unsigned short* P   = (unsigned short*)ws;
    unsigned short* Xs  = (unsigned short*)(ws + P_BYTES);
    unsigned short* Wsp = (unsigned short*)(ws + P_BYTES + XS_BYTES);
    float* bias    = (float*)(ws + P_BYTES + XS_BYTES + WS_BYTES);
    float* leafsum = (float*)(ws + P_BYTES + XS_BYTES + WS_BYTES + 4096);

    hipMemsetAsync(leafsum, 0, NLEAF * sizeof(float), stream);
    sdt_xsplit<<<BROWS * 100 / 256, 256, 0, stream>>>(X, Xs);
    sdt_wsplit<<<1024, 256, 0, stream>>>(Wi, Wsp, bias);
    sdt_gemm8<<<512, 512, 0, stream>>>(Xs, Wsp, bias, P);
    sdt_tree<<<BROWS / 32, 256, 0, stream>>>(P, Wl, Y, leafsum);
    sdt_penalty<<<1, 1024, 0, stream>>>(leafsum, pen);
}

// Round 14
// 172.856 us; speedup vs baseline: 1.0272x; 1.0272x over previous
//
#include <hip/hip_runtime.h>
#include <stdint.h>

// Soft Decision Tree forward, MI355X (gfx950)
//   xsplit: X -> Xs = bf16(X) [32768][800]                  (validated)
//   wsplit: W_inner -> Ws = bf16 [1024][800], bias[1024]    (validated)
//   gemm8 : P = sigmoid(bias + Xs @ Ws^T), K=800 bf16 MFMA  (r11/r13-validated, BYTE-IDENTICAL)
//   tree  : REWRITE (single kernel changed): shuffle-walk + direct-global expansion,
//           wl read from L2 (no 40KB LDS), no LDS p-row -> 29.7KB LDS, ~5 blocks/CU
//   penalty: tree reduction of leaf sums                    (validated)

#define BROWS 32768
#define KDIM  784
#define NNODE 1023
#define NP    1024
#define NLEAF 1024
#define OUTD  10
#define NDEPTH 10
#define LAMDA 1e-3f

#define GKS   800           // Xs row stride
#define GKW   800           // Ws row stride
#define NT    25            // K tiles of 32

typedef __attribute__((ext_vector_type(8))) short short8;
typedef __attribute__((ext_vector_type(4))) float f32x4;

__device__ __forceinline__ unsigned short f2bf(float f) {
    unsigned int u = __float_as_uint(f);
    u = u + 0x7FFFu + ((u >> 16) & 1u);   // RNE
    return (unsigned short)(u >> 16);
}
__device__ __forceinline__ float bf2f(unsigned short h) {
    return __uint_as_float(((unsigned int)h) << 16);
}

// ============================ Pass X: cast X -> bf16 =============================
__global__ __launch_bounds__(256)
void sdt_xsplit(const float* __restrict__ X, unsigned short* __restrict__ Xs)
{
    const int g   = blockIdx.x * 256 + threadIdx.x;   // [0, 32768*100)
    const int row = g / 100, grp = g % 100;
    unsigned int hi[4];
    if (grp < 98) {
        const float4* src = reinterpret_cast<const float4*>(&X[(size_t)row * KDIM + grp * 8]);
        const float4 v0 = src[0], v1 = src[1];
        const float v[8] = {v0.x, v0.y, v0.z, v0.w, v1.x, v1.y, v1.z, v1.w};
#pragma unroll
        for (int i = 0; i < 4; ++i)
            hi[i] = (unsigned int)f2bf(v[2*i]) | ((unsigned int)f2bf(v[2*i+1]) << 16);
    } else {
#pragma unroll
        for (int i = 0; i < 4; ++i) hi[i] = 0u;
    }
    *reinterpret_cast<uint4*>(&Xs[(size_t)row * GKS + grp * 8]) = make_uint4(hi[0], hi[1], hi[2], hi[3]);
}

// ============================ Pass W: cast W -> bf16 =============================
__global__ __launch_bounds__(256)
void sdt_wsplit(const float* __restrict__ Wi, unsigned short* __restrict__ Ws,
                float* __restrict__ bias)
{
    const int row = blockIdx.x;          // 0..1023
    const int tid = threadIdx.x;
    for (int c = tid; c < GKW; c += 256) {
        unsigned short v = 0;
        if (row < NNODE && c < KDIM) v = f2bf(Wi[(size_t)row * (KDIM + 1) + 1 + c]);
        Ws[(size_t)row * GKW + c] = v;
    }
    if (tid == 0) bias[row] = (row < NNODE) ? Wi[(size_t)row * (KDIM + 1)] : 0.f;
}

// ===================== Pass A: 256x256, BK=32, 4-buffer counted-vmcnt MFMA =====================
#define BAR() { __builtin_amdgcn_sched_barrier(0); __builtin_amdgcn_s_barrier(); __builtin_amdgcn_sched_barrier(0); }

#define STAGE(ktn)                                                                    \
    {                                                                                 \
        const int kt_ = (ktn);                                                        \
        const int kk_ = kt_ * 32;                                                     \
        unsigned short* ab_ = lds + (kt_ & 3) * 16384;                                \
        unsigned short* bb_ = ab_ + 8192;                                             \
        _Pragma("unroll")                                                             \
        for (int j = 0; j < 2; ++j)                                                   \
            __builtin_amdgcn_global_load_lds(                                         \
                (const __attribute__((address_space(1))) void*)(pA[j] + kk_),         \
                (__attribute__((address_space(3))) void*)(ab_ + (j * 512 + wave * 64) * 8), \
                16, 0, 0);                                                            \
        _Pragma("unroll")                                                             \
        for (int j = 0; j < 2; ++j)                                                   \
            __builtin_amdgcn_global_load_lds(                                         \
                (const __attribute__((address_space(1))) void*)(pB[j] + kk_),         \
                (__attribute__((address_space(3))) void*)(bb_ + (j * 512 + wave * 64) * 8), \
                16, 0, 0);                                                            \
    }

#define LDA4(dst, mb, ab_)                                                            \
    _Pragma("unroll")                                                                 \
    for (int mi = 0; mi < 4; ++mi) {                                                  \
        const int row_ = wr * 128 + ((mb) + mi) * 16 + fr;                            \
        dst[mi] = *reinterpret_cast<const short8*>(                                   \
            (ab_) + row_ * 32 + ((q4 ^ ((row_ >> 1) & 3)) * 8));                      \
    }

#define LDB4(dst, bb_)                                                                \
    _Pragma("unroll")                                                                 \
    for (int n = 0; n < 4; ++n) {                                                     \
        const int row_ = wc * 64 + n * 16 + fr;                                       \
        dst[n] = *reinterpret_cast<const short8*>(                                    \
            (bb_) + row_ * 32 + ((q4 ^ ((row_ >> 1) & 3)) * 8));                      \
    }

#define MFMA16(mb, av, bv)                                                            \
    _Pragma("unroll")                                                                 \
    for (int mi = 0; mi < 4; ++mi)                                                    \
        _Pragma("unroll")                                                             \
        for (int n = 0; n < 4; ++n)                                                   \
            acc[(mb) + mi][n] = __builtin_amdgcn_mfma_f32_16x16x32_bf16(              \
                av[mi], bv[n], acc[(mb) + mi][n], 0, 0, 0);

__global__ __launch_bounds__(512, 2)
void sdt_gemm8(const unsigned short* __restrict__ Xs, const unsigned short* __restrict__ Ws,
               const float* __restrict__ bias, unsigned short* __restrict__ P)
{
    __shared__ __align__(16) unsigned short lds[65536];   // 128 KB

    const int tid  = threadIdx.x;
    const int wave = tid >> 6, lane = tid & 63;
    const int wr = wave >> 2, wc = wave & 3;
    const int b  = blockIdx.x;
    const int wg = (b & 7) * 64 + (b >> 3);
    const int col0 = (wg & 3) * 256;
    const int row0 = (wg >> 2) * 256;

    const int fr = lane & 15;
    const int q4 = lane >> 4;

    f32x4 acc[8][4];
#pragma unroll
    for (int i = 0; i < 8; ++i)
#pragma unroll
        for (int j = 0; j < 4; ++j) acc[i][j] = (f32x4)0.f;

    const unsigned short* pA[2];
    const unsigned short* pB[2];
#pragma unroll
    for (int j = 0; j < 2; ++j) {
        const int c = j * 512 + tid;
        const int r = c >> 2;
        const int kc = (c & 3) ^ ((r >> 1) & 3);
        pA[j] = Xs + (size_t)(row0 + r) * GKS + kc * 8;
        pB[j] = Ws + (size_t)(col0 + r) * GKW + kc * 8;
    }

    STAGE(0);
    STAGE(1);
    asm volatile("s_waitcnt vmcnt(4)" ::: "memory");
    BAR();

#pragma unroll 1
    for (int kt = 0; kt < NT; ++kt) {
        const unsigned short* ab = lds + (kt & 3) * 16384;
        const unsigned short* bb = ab + 8192;
        short8 a[4], bfr[4];

        LDA4(a, 0, ab);
        LDB4(bfr, bb);
        if (kt + 2 < NT) STAGE(kt + 2);
        BAR();
        __builtin_amdgcn_s_setprio(1);
        MFMA16(0, a, bfr);
        __builtin_amdgcn_s_setprio(0);
        BAR();
        LDA4(a, 4, ab);
        if (kt < NT - 2) { asm volatile("s_waitcnt vmcnt(4)" ::: "memory"); }
        else             { asm volatile("s_waitcnt vmcnt(0)" ::: "memory"); }
        BAR();
        __builtin_amdgcn_s_setprio(1);
        MFMA16(4, a, bfr);
        __builtin_amdgcn_s_setprio(0);
        BAR();
    }

    __syncthreads();
    unsigned short* tr = lds + wave * 8192;
    float bv[4];
#pragma unroll
    for (int n = 0; n < 4; ++n) bv[n] = bias[col0 + wc * 64 + n * 16 + fr];

#pragma unroll
    for (int m = 0; m < 8; ++m)
#pragma unroll
        for (int reg = 0; reg < 4; ++reg) {
            const int rl = m * 16 + q4 * 4 + reg;
#pragma unroll
            for (int n = 0; n < 4; ++n) {
                const float z = acc[m][n][reg] + bv[n];
                const float p = 1.f / (1.f + __expf(-z));
                tr[rl * 64 + n * 16 + fr] = f2bf(p);
            }
        }
#pragma unroll
    for (int it = 0; it < 16; ++it) {
        const int r  = it * 8 + (lane >> 3);
        const int c8 = (lane & 7) * 8;
        const uint4 v = *reinterpret_cast<const uint4*>(tr + r * 64 + c8);
        *reinterpret_cast<uint4*>(
            &P[(size_t)(row0 + wr * 128 + r) * NP + col0 + wc * 64 + c8]) = v;
    }
}

// ===================== Pass B: tree sweep + leaf GEMV + leaf sums =====================
// v3: shuffle-walk (preg = flat nodes 0..63, 6x __shfl) + direct coalesced global
// loads for levels 6-9 (aligned vectors + shfl_up(1) + lane-0 patch); wl from L2.
// LDS: only y-reduce scratch (stride 13) + leaf-sum combine -> ~29.7 KB.
__global__ __launch_bounds__(256)
void sdt_tree(const unsigned short* __restrict__ P, const float* __restrict__ Wl,
              float* __restrict__ Y, float* __restrict__ leafsum)
{
    __shared__ float rd[4][832];         // 13312 B (y reduction, stride 13)
    __shared__ float lsb[4][1024];       // 16384 B (leaf-sum combine)
    const int tid = threadIdx.x;
    const int wave = tid >> 6, lane = tid & 63;

    float lsum[16];
#pragma unroll
    for (int i = 0; i < 16; ++i) lsum[i] = 0.f;

    float* rw = rd[wave];
    const int rowbase = blockIdx.x * 32 + wave * 8;
    const int o_r   = lane % 10;            // reduction role (lanes < 40)
    const int seg16 = (lane / 10) * 16;

#pragma unroll 2
    for (int r = 0; r < 8; ++r) {
        const int row = rowbase + r;
        const unsigned short* pr = P + (size_t)row * NP;

        // flat nodes 0..63 in registers across lanes (one coalesced 2B load)
        const float preg = bf2f(pr[lane]);

        // walk levels 0-5: flat child f' = 2f+1+bit; p[f] via bpermute
        float mu = 1.f; int f = 0;
#pragma unroll
        for (int d = 0; d < 6; ++d) {
            const int bit = (lane >> (5 - d)) & 1;
            const float pv = __shfl(preg, f, 64);
            mu *= bit ? (1.f - pv) : pv;
            f = 2 * f + 1 + bit;
        }

        // level 6: flat col 63+lane (2B coalesced)
        const float p6 = bf2f(pr[63 + lane]);
        float m1[2];
        m1[0] = mu * p6; m1[1] = mu * (1.f - p6);

        // level 7: need flat cols 127+2l, 128+2l
        const unsigned int u7 = *reinterpret_cast<const unsigned int*>(pr + 128 + 2 * lane);
        const float lo7 = bf2f((unsigned short)(u7 & 0xffffu));   // col 128+2l
        const float hi7 = bf2f((unsigned short)(u7 >> 16));       // col 129+2l
        float e7 = __shfl_up(hi7, 1, 64);                         // lane l: col 127+2l
        if (lane == 0) e7 = bf2f(pr[127]);
        float m2[4];
        m2[0] = m1[0] * e7;  m2[1] = m1[0] * (1.f - e7);
        m2[2] = m1[1] * lo7; m2[3] = m1[1] * (1.f - lo7);

        // level 8: need flat cols 255+4l..258+4l
        const uint2 u8 = *reinterpret_cast<const uint2*>(pr + 256 + 4 * lane);
        const float a0 = bf2f((unsigned short)(u8.x & 0xffffu));  // 256+4l
        const float a1 = bf2f((unsigned short)(u8.x >> 16));      // 257+4l
        const float a2 = bf2f((unsigned short)(u8.y & 0xffffu));  // 258+4l
        const float a3 = bf2f((unsigned short)(u8.y >> 16));      // 259+4l (for lane l+1)
        float e8 = __shfl_up(a3, 1, 64);                          // lane l: col 255+4l
        if (lane == 0) e8 = bf2f(pr[255]);
        const float p8v[4] = {e8, a0, a1, a2};
        float m3[8];
#pragma unroll
        for (int i = 0; i < 4; ++i) {
            m3[2 * i] = m2[i] * p8v[i]; m3[2 * i + 1] = m2[i] * (1.f - p8v[i]);
        }

        // level 9: need flat cols 511+8l..518+8l
        const uint4 u9 = *reinterpret_cast<const uint4*>(pr + 512 + 8 * lane);
        const float b0 = bf2f((unsigned short)(u9.x & 0xffffu));  // 512+8l
        const float b1 = bf2f((unsigned short)(u9.x >> 16));
        const float b2 = bf2f((unsigned short)(u9.y & 0xffffu));
        const float b3 = bf2f((unsigned short)(u9.y >> 16));
        const float b4 = bf2f((unsigned short)(u9.z & 0xffffu));
        const float b5 = bf2f((unsigned short)(u9.z >> 16));
        const float b6 = bf2f((unsigned short)(u9.w & 0xffffu));  // 518+8l
        const float b7 = bf2f((unsigned short)(u9.w >> 16));      // 519+8l (for lane l+1)
        float e9 = __shfl_up(b7, 1, 64);                          // lane l: col 511+8l
        if (lane == 0) e9 = bf2f(pr[511]);
        const float p9v[8] = {e9, b0, b1, b2, b3, b4, b5, b6};
        float m4[16];
#pragma unroll
        for (int i = 0; i < 8; ++i) {
            m4[2 * i] = m3[i] * p9v[i]; m4[2 * i + 1] = m3[i] * (1.f - p9v[i]);
        }
#pragma unroll
        for (int i = 0; i < 16; ++i) lsum[i] += m4[i];

        // y partials: lane owns leaves lane*16..+15; wl from global (L2-resident)
#pragma unroll
        for (int o = 0; o < OUTD; ++o) {
            float s = 0.f;
#pragma unroll
            for (int i4 = 0; i4 < 4; ++i4) {
                const float4 w4 = *reinterpret_cast<const float4*>(
                    &Wl[o * NLEAF + lane * 16 + i4 * 4]);
                s = fmaf(m4[4 * i4 + 0], w4.x, s);
                s = fmaf(m4[4 * i4 + 1], w4.y, s);
                s = fmaf(m4[4 * i4 + 2], w4.z, s);
                s = fmaf(m4[4 * i4 + 3], w4.w, s);
            }
            rw[lane * 13 + o] = s;
        }
        // reduce 64 partials per output via LDS transpose + 2 shuffles (r11 form)
        float s = 0.f;
        if (lane < 40) {
#pragma unroll
            for (int m = 0; m < 16; ++m) s += rw[(seg16 + m) * 13 + o_r];
        }
        s += __shfl_down(s, 20, 64);
        s += __shfl_down(s, 10, 64);
        if (lane < 10) Y[(size_t)row * OUTD + lane] = s;
    }

    // ---- leaf sums ----
#pragma unroll
    for (int i = 0; i < 16; ++i) {
        const int ii = (i + lane) & 15;
        lsb[wave][lane * 16 + ii] = lsum[ii];
    }
    __syncthreads();
    for (int idx = tid; idx < NLEAF; idx += 256) {
        const float s = lsb[0][idx] + lsb[1][idx] + lsb[2][idx] + lsb[3][idx];
        atomicAdd(&leafsum[idx], s);
    }
}

// ============================ Pass C: penalty ============================
__global__ __launch_bounds__(1024)
void sdt_penalty(const float* __restrict__ leafsum, float* __restrict__ pen_out)
{
    __shared__ float t[NLEAF];
    __shared__ float red1[1024];
    const int tid = threadIdx.x;
    t[tid] = leafsum[tid];
    __syncthreads();
    float pen = 0.f;
    for (int d = NDEPTH; d >= 1; --d) {
        const int n = 1 << d;
        if (tid < n) {
            const float num = t[tid];
            const float par = t[tid & ~1] + t[tid | 1];
            const float a = num / par;
            const float coeff = LAMDA * exp2f((float)(1 - d));
            pen -= 0.5f * coeff * (logf(a) + logf(1.f - a));
        }
        float s = 0.f;
        if (tid < (n >> 1)) s = t[2 * tid] + t[2 * tid + 1];
        __syncthreads();
        if (tid < (n >> 1)) t[tid] = s;
        __syncthreads();
    }
    red1[tid] = pen;
    __syncthreads();
    for (int off = 512; off >= 1; off >>= 1) {
        if (tid < off) red1[tid] += red1[tid + off];
        __syncthreads();
    }
    if (tid == 0) pen_out[0] = red1[0];
}

// ================================ launch ================================
extern "C" void kernel_launch(void* const* d_in, const int* in_sizes, int n_in,
                              void* d_out, int out_size, void* d_ws, size_t ws_size,
                              hipStream_t stream)
{
    const float* X  = (const float*)d_in[0];
    const float* Wi = (const float*)d_in[1];
    const float* Wl = (const float*)d_in[2];
    float* Y   = (float*)d_out;
    float* pen = Y + (size_t)BROWS * OUTD;

    char* ws = (char*)d_ws;
    const size_t P_BYTES  = (size_t)BROWS * NP * 2;            // 67,108,864
    const size_t XS_BYTES = (size_t)BROWS * GKS * 2;           // 52,428,800
    const size_t WS_BYTES = (size_t)NP * GKW * 2;              // 1,638,400

    unsigned short* P   = (unsigned short*)ws;
    unsigned short* Xs  = (unsigned short*)(ws + P_BYTES);
    unsigned short* Wsp = (unsigned short*)(ws + P_BYTES + XS_BYTES);
    float* bias    = (float*)(ws + P_BYTES + XS_BYTES + WS_BYTES);
    float* leafsum = (float*)(ws + P_BYTES + XS_BYTES + WS_BYTES + 4096);

    hipMemsetAsync(leafsum, 0, NLEAF * sizeof(float), stream);
    sdt_xsplit<<<BROWS * 100 / 256, 256, 0, stream>>>(X, Xs);
    sdt_wsplit<<<1024, 256, 0, stream>>>(Wi, Wsp, bias);
    sdt_gemm8<<<512, 512, 0, stream>>>(Xs, Wsp, bias, P);
    sdt_tree<<<BROWS / 32, 256, 0, stream>>>(P, Wl, Y, leafsum);
    sdt_penalty<<<1, 1024, 0, stream>>>(leafsum, pen);
}

// Round 15
// 171.792 us; speedup vs baseline: 1.0336x; 1.0062x over previous
//
#include <hip/hip_runtime.h>
#include <stdint.h>

// Soft Decision Tree forward, MI355X (gfx950)
//   xsplit: X -> Xs = bf16(X) [32768][800]                  (validated)
//   wsplit: W_inner -> Ws = bf16 [1024][800], bias[1024]    (validated)
//   gemm8 : P = sigmoid(bias + Xs @ Ws^T), K=800 bf16 MFMA  (r11/r13/r14-validated, BYTE-IDENTICAL)
//   tree  : r14 shuffle-walk + SINGLE CHANGE: W_leaf register-resident
//           (wreg[10][4] float4 loaded once/lane; GEMV = pure register FMA)
//   penalty: tree reduction of leaf sums                    (validated)

#define BROWS 32768
#define KDIM  784
#define NNODE 1023
#define NP    1024
#define NLEAF 1024
#define OUTD  10
#define NDEPTH 10
#define LAMDA 1e-3f

#define GKS   800           // Xs row stride
#define GKW   800           // Ws row stride
#define NT    25            // K tiles of 32

typedef __attribute__((ext_vector_type(8))) short short8;
typedef __attribute__((ext_vector_type(4))) float f32x4;

__device__ __forceinline__ unsigned short f2bf(float f) {
    unsigned int u = __float_as_uint(f);
    u = u + 0x7FFFu + ((u >> 16) & 1u);   // RNE
    return (unsigned short)(u >> 16);
}
__device__ __forceinline__ float bf2f(unsigned short h) {
    return __uint_as_float(((unsigned int)h) << 16);
}

// ============================ Pass X: cast X -> bf16 =============================
__global__ __launch_bounds__(256)
void sdt_xsplit(const float* __restrict__ X, unsigned short* __restrict__ Xs)
{
    const int g   = blockIdx.x * 256 + threadIdx.x;   // [0, 32768*100)
    const int row = g / 100, grp = g % 100;
    unsigned int hi[4];
    if (grp < 98) {
        const float4* src = reinterpret_cast<const float4*>(&X[(size_t)row * KDIM + grp * 8]);
        const float4 v0 = src[0], v1 = src[1];
        const float v[8] = {v0.x, v0.y, v0.z, v0.w, v1.x, v1.y, v1.z, v1.w};
#pragma unroll
        for (int i = 0; i < 4; ++i)
            hi[i] = (unsigned int)f2bf(v[2*i]) | ((unsigned int)f2bf(v[2*i+1]) << 16);
    } else {
#pragma unroll
        for (int i = 0; i < 4; ++i) hi[i] = 0u;
    }
    *reinterpret_cast<uint4*>(&Xs[(size_t)row * GKS + grp * 8]) = make_uint4(hi[0], hi[1], hi[2], hi[3]);
}

// ============================ Pass W: cast W -> bf16 =============================
__global__ __launch_bounds__(256)
void sdt_wsplit(const float* __restrict__ Wi, unsigned short* __restrict__ Ws,
                float* __restrict__ bias)
{
    const int row = blockIdx.x;          // 0..1023
    const int tid = threadIdx.x;
    for (int c = tid; c < GKW; c += 256) {
        unsigned short v = 0;
        if (row < NNODE && c < KDIM) v = f2bf(Wi[(size_t)row * (KDIM + 1) + 1 + c]);
        Ws[(size_t)row * GKW + c] = v;
    }
    if (tid == 0) bias[row] = (row < NNODE) ? Wi[(size_t)row * (KDIM + 1)] : 0.f;
}

// ===================== Pass A: 256x256, BK=32, 4-buffer counted-vmcnt MFMA =====================
#define BAR() { __builtin_amdgcn_sched_barrier(0); __builtin_amdgcn_s_barrier(); __builtin_amdgcn_sched_barrier(0); }

#define STAGE(ktn)                                                                    \
    {                                                                                 \
        const int kt_ = (ktn);                                                        \
        const int kk_ = kt_ * 32;                                                     \
        unsigned short* ab_ = lds + (kt_ & 3) * 16384;                                \
        unsigned short* bb_ = ab_ + 8192;                                             \
        _Pragma("unroll")                                                             \
        for (int j = 0; j < 2; ++j)                                                   \
            __builtin_amdgcn_global_load_lds(                                         \
                (const __attribute__((address_space(1))) void*)(pA[j] + kk_),         \
                (__attribute__((address_space(3))) void*)(ab_ + (j * 512 + wave * 64) * 8), \
                16, 0, 0);                                                            \
        _Pragma("unroll")                                                             \
        for (int j = 0; j < 2; ++j)                                                   \
            __builtin_amdgcn_global_load_lds(                                         \
                (const __attribute__((address_space(1))) void*)(pB[j] + kk_),         \
                (__attribute__((address_space(3))) void*)(bb_ + (j * 512 + wave * 64) * 8), \
                16, 0, 0);                                                            \
    }

#define LDA4(dst, mb, ab_)                                                            \
    _Pragma("unroll")                                                                 \
    for (int mi = 0; mi < 4; ++mi) {                                                  \
        const int row_ = wr * 128 + ((mb) + mi) * 16 + fr;                            \
        dst[mi] = *reinterpret_cast<const short8*>(                                   \
            (ab_) + row_ * 32 + ((q4 ^ ((row_ >> 1) & 3)) * 8));                      \
    }

#define LDB4(dst, bb_)                                                                \
    _Pragma("unroll")                                                                 \
    for (int n = 0; n < 4; ++n) {                                                     \
        const int row_ = wc * 64 + n * 16 + fr;                                       \
        dst[n] = *reinterpret_cast<const short8*>(                                    \
            (bb_) + row_ * 32 + ((q4 ^ ((row_ >> 1) & 3)) * 8));                      \
    }

#define MFMA16(mb, av, bv)                                                            \
    _Pragma("unroll")                                                                 \
    for (int mi = 0; mi < 4; ++mi)                                                    \
        _Pragma("unroll")                                                             \
        for (int n = 0; n < 4; ++n)                                                   \
            acc[(mb) + mi][n] = __builtin_amdgcn_mfma_f32_16x16x32_bf16(              \
                av[mi], bv[n], acc[(mb) + mi][n], 0, 0, 0);

__global__ __launch_bounds__(512, 2)
void sdt_gemm8(const unsigned short* __restrict__ Xs, const unsigned short* __restrict__ Ws,
               const float* __restrict__ bias, unsigned short* __restrict__ P)
{
    __shared__ __align__(16) unsigned short lds[65536];   // 128 KB

    const int tid  = threadIdx.x;
    const int wave = tid >> 6, lane = tid & 63;
    const int wr = wave >> 2, wc = wave & 3;
    const int b  = blockIdx.x;
    const int wg = (b & 7) * 64 + (b >> 3);
    const int col0 = (wg & 3) * 256;
    const int row0 = (wg >> 2) * 256;

    const int fr = lane & 15;
    const int q4 = lane >> 4;

    f32x4 acc[8][4];
#pragma unroll
    for (int i = 0; i < 8; ++i)
#pragma unroll
        for (int j = 0; j < 4; ++j) acc[i][j] = (f32x4)0.f;

    const unsigned short* pA[2];
    const unsigned short* pB[2];
#pragma unroll
    for (int j = 0; j < 2; ++j) {
        const int c = j * 512 + tid;
        const int r = c >> 2;
        const int kc = (c & 3) ^ ((r >> 1) & 3);
        pA[j] = Xs + (size_t)(row0 + r) * GKS + kc * 8;
        pB[j] = Ws + (size_t)(col0 + r) * GKW + kc * 8;
    }

    STAGE(0);
    STAGE(1);
    asm volatile("s_waitcnt vmcnt(4)" ::: "memory");
    BAR();

#pragma unroll 1
    for (int kt = 0; kt < NT; ++kt) {
        const unsigned short* ab = lds + (kt & 3) * 16384;
        const unsigned short* bb = ab + 8192;
        short8 a[4], bfr[4];

        LDA4(a, 0, ab);
        LDB4(bfr, bb);
        if (kt + 2 < NT) STAGE(kt + 2);
        BAR();
        __builtin_amdgcn_s_setprio(1);
        MFMA16(0, a, bfr);
        __builtin_amdgcn_s_setprio(0);
        BAR();
        LDA4(a, 4, ab);
        if (kt < NT - 2) { asm volatile("s_waitcnt vmcnt(4)" ::: "memory"); }
        else             { asm volatile("s_waitcnt vmcnt(0)" ::: "memory"); }
        BAR();
        __builtin_amdgcn_s_setprio(1);
        MFMA16(4, a, bfr);
        __builtin_amdgcn_s_setprio(0);
        BAR();
    }

    __syncthreads();
    unsigned short* tr = lds + wave * 8192;
    float bv[4];
#pragma unroll
    for (int n = 0; n < 4; ++n) bv[n] = bias[col0 + wc * 64 + n * 16 + fr];

#pragma unroll
    for (int m = 0; m < 8; ++m)
#pragma unroll
        for (int reg = 0; reg < 4; ++reg) {
            const int rl = m * 16 + q4 * 4 + reg;
#pragma unroll
            for (int n = 0; n < 4; ++n) {
                const float z = acc[m][n][reg] + bv[n];
                const float p = 1.f / (1.f + __expf(-z));
                tr[rl * 64 + n * 16 + fr] = f2bf(p);
            }
        }
#pragma unroll
    for (int it = 0; it < 16; ++it) {
        const int r  = it * 8 + (lane >> 3);
        const int c8 = (lane & 7) * 8;
        const uint4 v = *reinterpret_cast<const uint4*>(tr + r * 64 + c8);
        *reinterpret_cast<uint4*>(
            &P[(size_t)(row0 + wr * 128 + r) * NP + col0 + wc * 64 + c8]) = v;
    }
}

// ===================== Pass B: tree sweep + leaf GEMV + leaf sums =====================
// r14 shuffle-walk structure, byte-identical except: W_leaf held in REGISTERS
// (wreg[10][4] float4 per lane, loaded once) -> wl traffic 1.31GB -> ~0.
__global__ __launch_bounds__(256)
void sdt_tree(const unsigned short* __restrict__ P, const float* __restrict__ Wl,
              float* __restrict__ Y, float* __restrict__ leafsum)
{
    __shared__ float rd[4][832];         // 13312 B (y reduction, stride 13)
    __shared__ float lsb[4][1024];       // 16384 B (leaf-sum combine)
    const int tid = threadIdx.x;
    const int wave = tid >> 6, lane = tid & 63;

    float lsum[16];
#pragma unroll
    for (int i = 0; i < 16; ++i) lsum[i] = 0.f;

    // W_leaf register-resident: lane owns leaves lane*16..+15 for all 10 outputs
    float4 wreg[OUTD][4];
#pragma unroll
    for (int o = 0; o < OUTD; ++o)
#pragma unroll
        for (int i4 = 0; i4 < 4; ++i4)
            wreg[o][i4] = *reinterpret_cast<const float4*>(
                &Wl[o * NLEAF + lane * 16 + i4 * 4]);

    float* rw = rd[wave];
    const int rowbase = blockIdx.x * 32 + wave * 8;
    const int o_r   = lane % 10;            // reduction role (lanes < 40)
    const int seg16 = (lane / 10) * 16;

#pragma unroll 2
    for (int r = 0; r < 8; ++r) {
        const int row = rowbase + r;
        const unsigned short* pr = P + (size_t)row * NP;

        // flat nodes 0..63 in registers across lanes (one coalesced 2B load)
        const float preg = bf2f(pr[lane]);

        // walk levels 0-5: flat child f' = 2f+1+bit; p[f] via bpermute
        float mu = 1.f; int f = 0;
#pragma unroll
        for (int d = 0; d < 6; ++d) {
            const int bit = (lane >> (5 - d)) & 1;
            const float pv = __shfl(preg, f, 64);
            mu *= bit ? (1.f - pv) : pv;
            f = 2 * f + 1 + bit;
        }

        // level 6: flat col 63+lane (2B coalesced)
        const float p6 = bf2f(pr[63 + lane]);
        float m1[2];
        m1[0] = mu * p6; m1[1] = mu * (1.f - p6);

        // level 7: need flat cols 127+2l, 128+2l
        const unsigned int u7 = *reinterpret_cast<const unsigned int*>(pr + 128 + 2 * lane);
        const float lo7 = bf2f((unsigned short)(u7 & 0xffffu));   // col 128+2l
        const float hi7 = bf2f((unsigned short)(u7 >> 16));       // col 129+2l
        float e7 = __shfl_up(hi7, 1, 64);                         // lane l: col 127+2l
        if (lane == 0) e7 = bf2f(pr[127]);
        float m2[4];
        m2[0] = m1[0] * e7;  m2[1] = m1[0] * (1.f - e7);
        m2[2] = m1[1] * lo7; m2[3] = m1[1] * (1.f - lo7);

        // level 8: need flat cols 255+4l..258+4l
        const uint2 u8 = *reinterpret_cast<const uint2*>(pr + 256 + 4 * lane);
        const float a0 = bf2f((unsigned short)(u8.x & 0xffffu));  // 256+4l
        const float a1 = bf2f((unsigned short)(u8.x >> 16));      // 257+4l
        const float a2 = bf2f((unsigned short)(u8.y & 0xffffu));  // 258+4l
        const float a3 = bf2f((unsigned short)(u8.y >> 16));      // 259+4l (for lane l+1)
        float e8 = __shfl_up(a3, 1, 64);                          // lane l: col 255+4l
        if (lane == 0) e8 = bf2f(pr[255]);
        const float p8v[4] = {e8, a0, a1, a2};
        float m3[8];
#pragma unroll
        for (int i = 0; i < 4; ++i) {
            m3[2 * i] = m2[i] * p8v[i]; m3[2 * i + 1] = m2[i] * (1.f - p8v[i]);
        }

        // level 9: need flat cols 511+8l..518+8l
        const uint4 u9 = *reinterpret_cast<const uint4*>(pr + 512 + 8 * lane);
        const float b0 = bf2f((unsigned short)(u9.x & 0xffffu));  // 512+8l
        const float b1 = bf2f((unsigned short)(u9.x >> 16));
        const float b2 = bf2f((unsigned short)(u9.y & 0xffffu));
        const float b3 = bf2f((unsigned short)(u9.y >> 16));
        const float b4 = bf2f((unsigned short)(u9.z & 0xffffu));
        const float b5 = bf2f((unsigned short)(u9.z >> 16));
        const float b6 = bf2f((unsigned short)(u9.w & 0xffffu));  // 518+8l
        const float b7 = bf2f((unsigned short)(u9.w >> 16));      // 519+8l (for lane l+1)
        float e9 = __shfl_up(b7, 1, 64);                          // lane l: col 511+8l
        if (lane == 0) e9 = bf2f(pr[511]);
        const float p9v[8] = {e9, b0, b1, b2, b3, b4, b5, b6};
        float m4[16];
#pragma unroll
        for (int i = 0; i < 8; ++i) {
            m4[2 * i] = m3[i] * p9v[i]; m4[2 * i + 1] = m3[i] * (1.f - p9v[i]);
        }
#pragma unroll
        for (int i = 0; i < 16; ++i) lsum[i] += m4[i];

        // y partials: pure register FMA against wreg (same ascending-i order)
#pragma unroll
        for (int o = 0; o < OUTD; ++o) {
            float s = 0.f;
#pragma unroll
            for (int i4 = 0; i4 < 4; ++i4) {
                const float4 w4 = wreg[o][i4];
                s = fmaf(m4[4 * i4 + 0], w4.x, s);
                s = fmaf(m4[4 * i4 + 1], w4.y, s);
                s = fmaf(m4[4 * i4 + 2], w4.z, s);
                s = fmaf(m4[4 * i4 + 3], w4.w, s);
            }
            rw[lane * 13 + o] = s;
        }
        // reduce 64 partials per output via LDS transpose + 2 shuffles (r11 form)
        float s = 0.f;
        if (lane < 40) {
#pragma unroll
            for (int m = 0; m < 16; ++m) s += rw[(seg16 + m) * 13 + o_r];
        }
        s += __shfl_down(s, 20, 64);
        s += __shfl_down(s, 10, 64);
        if (lane < 10) Y[(size_t)row * OUTD + lane] = s;
    }

    // ---- leaf sums ----
#pragma unroll
    for (int i = 0; i < 16; ++i) {
        const int ii = (i + lane) & 15;
        lsb[wave][lane * 16 + ii] = lsum[ii];
    }
    __syncthreads();
    for (int idx = tid; idx < NLEAF; idx += 256) {
        const float s = lsb[0][idx] + lsb[1][idx] + lsb[2][idx] + lsb[3][idx];
        atomicAdd(&leafsum[idx], s);
    }
}

// ============================ Pass C: penalty ============================
__global__ __launch_bounds__(1024)
void sdt_penalty(const float* __restrict__ leafsum, float* __restrict__ pen_out)
{
    __shared__ float t[NLEAF];
    __shared__ float red1[1024];
    const int tid = threadIdx.x;
    t[tid] = leafsum[tid];
    __syncthreads();
    float pen = 0.f;
    for (int d = NDEPTH; d >= 1; --d) {
        const int n = 1 << d;
        if (tid < n) {
            const float num = t[tid];
            const float par = t[tid & ~1] + t[tid | 1];
            const float a = num / par;
            const float coeff = LAMDA * exp2f((float)(1 - d));
            pen -= 0.5f * coeff * (logf(a) + logf(1.f - a));
        }
        float s = 0.f;
        if (tid < (n >> 1)) s = t[2 * tid] + t[2 * tid + 1];
        __syncthreads();
        if (tid < (n >> 1)) t[tid] = s;
        __syncthreads();
    }
    red1[tid] = pen;
    __syncthreads();
    for (int off = 512; off >= 1; off >>= 1) {
        if (tid < off) red1[tid] += red1[tid + off];
        __syncthreads();
    }
    if (tid == 0) pen_out[0] = red1[0];
}

// ================================ launch ================================
extern "C" void kernel_launch(void* const* d_in, const int* in_sizes, int n_in,
                              void* d_out, int out_size, void* d_ws, size_t ws_size,
                              hipStream_t stream)
{
    const float* X  = (const float*)d_in[0];
    const float* Wi = (const float*)d_in[1];
    const float* Wl = (const float*)d_in[2];
    float* Y   = (float*)d_out;
    float* pen = Y + (size_t)BROWS * OUTD;

    char* ws = (char*)d_ws;
    const size_t P_BYTES  = (size_t)BROWS * NP * 2;            // 67,108,864
    const size_t XS_BYTES = (size_t)BROWS * GKS * 2;           // 52,428,800
    const size_t WS_BYTES = (size_t)NP * GKW * 2;              // 1,638,400

    unsigned short* P   = (unsigned short*)ws;
    unsigned short* Xs  = (unsigned short*)(ws + P_BYTES);
    unsigned short* Wsp = (unsigned short*)(ws + P_BYTES + XS_BYTES);
    float* bias    = (float*)(ws + P_BYTES + XS_BYTES + WS_BYTES);
    float* leafsum = (float*)(ws + P_BYTES + XS_BYTES + WS_BYTES + 4096);

    hipMemsetAsync(leafsum, 0, NLEAF * sizeof(float), stream);
    sdt_xsplit<<<BROWS * 100 / 256, 256, 0, stream>>>(X, Xs);
    sdt_wsplit<<<1024, 256, 0, stream>>>(Wi, Wsp, bias);
    sdt_gemm8<<<512, 512, 0, stream>>>(Xs, Wsp, bias, P);
    sdt_tree<<<BROWS / 32, 256, 0, stream>>>(P, Wl, Y, leafsum);
    sdt_penalty<<<1, 1024, 0, stream>>>(leafsum, pen);
}